// Round 14
// baseline (134.984 us; speedup 1.0000x reference)
//
#include <hip/hip_runtime.h>

#define DMODEL 1024
#define NHEADS 16
#define HDIM   64
#define BATCH  2
#define SEQ    2048
#define MROWS  (BATCH*SEQ)

typedef __bf16 bf16x8 __attribute__((ext_vector_type(8)));
typedef __bf16 bf16x4 __attribute__((ext_vector_type(4)));
typedef float floatx4 __attribute__((ext_vector_type(4)));
typedef float floatx16 __attribute__((ext_vector_type(16)));
typedef unsigned int uintx2 __attribute__((ext_vector_type(2)));

typedef const __attribute__((address_space(1))) void gvoid;
typedef __attribute__((address_space(3))) void lvoid;

// Q pre-scale: 1/sqrt(64) * log2(e), folded into the QKV GEMM epilogue.
#define QSCALE 0.18033688011112042f

__device__ inline unsigned cvtpk(float lo, float hi) {
  unsigned w;
  asm("v_cvt_pk_bf16_f32 %0, %1, %2" : "=v"(w) : "v"(lo), "v"(hi));
  return w;
}

// Single cast kernel: x (1048576 float4) then Wq/Wk/Wv/Wo (262144 float4 each).
__global__ void cast_all(const float* __restrict__ x,
                         const float* __restrict__ wq, const float* __restrict__ wk,
                         const float* __restrict__ wv, const float* __restrict__ wo,
                         __bf16* __restrict__ xb, __bf16* __restrict__ wqb,
                         __bf16* __restrict__ wkb, __bf16* __restrict__ wvb,
                         __bf16* __restrict__ wob)
{
  const int i = blockIdx.x * 256 + threadIdx.x;
  const float* s; __bf16* o; int off;
  if (i < MROWS*DMODEL/4) { s = x; o = xb; off = i; }
  else {
    const int r = i - MROWS*DMODEL/4;
    const int w = r >> 18;
    off = r & 262143;
    s = (w == 0) ? wq : (w == 1) ? wk : (w == 2) ? wv : wo;
    o = (w == 0) ? wqb : (w == 1) ? wkb : (w == 2) ? wvb : wob;
  }
  const float4 f = ((const float4*)s)[off];
  bf16x4 v = {(__bf16)f.x, (__bf16)f.y, (__bf16)f.z, (__bf16)f.w};
  *(bf16x4*)(o + off*4) = v;
}

// NT GEMM (unchanged): double-buffered gload_lds + vmcnt(4).
template<int MODE>
__global__ __launch_bounds__(256, 3)
void gemm_nt(const unsigned short* __restrict__ A,
             const unsigned short* __restrict__ W0,
             const unsigned short* __restrict__ W1,
             const unsigned short* __restrict__ W2,
             const float* __restrict__ b0,
             const float* __restrict__ b1,
             const float* __restrict__ b2,
             unsigned short* __restrict__ qout,
             unsigned short* __restrict__ kout,
             unsigned short* __restrict__ vout,
             float* __restrict__ outf)
{
  const int K = DMODEL;
  __shared__ unsigned short As[2][128*32];
  __shared__ unsigned short Bs[2][128*32];
  const int tid  = threadIdx.x;
  const int wid  = tid >> 6;
  const int lane = tid & 63;

  const int lin = blockIdx.x;
  const int wg  = (MODE == 0) ? ((lin & 7)*96 + (lin >> 3))
                              : ((lin & 7)*32 + (lin >> 3));
  const int bx  = (MODE == 0) ? (wg % 24) : (wg & 7);
  const int by  = (MODE == 0) ? (wg / 24) : (wg >> 3);
  const int brow = by * 128;
  const int bcol = bx * 128;
  const int wr = (wid >> 1) * 64;
  const int wc = (wid & 1) * 64;

  int which = 0;
  const unsigned short* Bw = W0;
  const float* bias = b0;
  int bcolL = bcol;
  if (MODE == 0) {
    which = bcol >> 10;
    Bw   = which == 0 ? W0 : which == 1 ? W1 : W2;
    bias = which == 0 ? b0 : which == 1 ? b1 : b2;
    bcolL = bcol & 1023;
  }

  floatx4 acc[4][4] = {};

  const int sr = wid*16 + (lane >> 2);
  const int sc = (lane & 3) * 8;
  const int fr = lane & 15;
  const int fk = (lane >> 4) * 8;

#define GSTAGE(KT, B) do {                                                     \
    _Pragma("unroll")                                                          \
    for (int i_ = 0; i_ < 2; ++i_) {                                           \
      __builtin_amdgcn_global_load_lds(                                        \
          (gvoid*)(A + (size_t)(brow + i_*64 + sr)*K + (KT) + sc),             \
          (lvoid*)(As[B] + i_*2048 + wid*512), 16, 0, 0);                      \
      __builtin_amdgcn_global_load_lds(                                        \
          (gvoid*)(Bw + (size_t)(bcolL + i_*64 + sr)*K + (KT) + sc),           \
          (lvoid*)(Bs[B] + i_*2048 + wid*512), 16, 0, 0);                      \
    }                                                                          \
  } while (0)

  GSTAGE(0, 0);

  for (int kt = 0; kt < K; kt += 32) {
    const int cur = (kt >> 5) & 1;
    if (kt + 32 < K) {
      GSTAGE(kt + 32, cur ^ 1);
      asm volatile("s_waitcnt vmcnt(4)" ::: "memory");
    } else {
      asm volatile("s_waitcnt vmcnt(0)" ::: "memory");
    }
    __builtin_amdgcn_s_barrier();
    __builtin_amdgcn_sched_barrier(0);

    bf16x8 af[4], bfv[4];
#pragma unroll
    for (int m = 0; m < 4; ++m)
      af[m] = *(const bf16x8*)(As[cur] + (wr + m*16 + fr)*32 + fk);
#pragma unroll
    for (int n = 0; n < 4; ++n)
      bfv[n] = *(const bf16x8*)(Bs[cur] + (wc + n*16 + fr)*32 + fk);
    __builtin_amdgcn_s_setprio(1);
#pragma unroll
    for (int m = 0; m < 4; ++m)
#pragma unroll
      for (int n = 0; n < 4; ++n)
        acc[m][n] = __builtin_amdgcn_mfma_f32_16x16x32_bf16(af[m], bfv[n], acc[m][n], 0, 0, 0);
    __builtin_amdgcn_s_setprio(0);
    __builtin_amdgcn_s_barrier();
  }
#undef GSTAGE

  const int er = (lane >> 4) * 4;
  const int ec = lane & 15;
#pragma unroll
  for (int m = 0; m < 4; ++m) {
#pragma unroll
    for (int n = 0; n < 4; ++n) {
      const int colL = bcolL + wc + n*16 + ec;
      const float bv = bias[colL];
      const int rowb = brow + wr + m*16 + er;
      if (MODE == 0) {
        const int bi = rowb >> 11, s = rowb & 2047;
        const int hh = colL >> 6, dd = colL & 63;
        if (which == 2) {
          bf16x4 v4 = {(__bf16)(acc[m][n][0] + bv), (__bf16)(acc[m][n][1] + bv),
                       (__bf16)(acc[m][n][2] + bv), (__bf16)(acc[m][n][3] + bv)};
          *(bf16x4*)((__bf16*)vout + ((size_t)(bi*NHEADS + hh)*HDIM + dd)*SEQ + s) = v4;
        } else if (which == 0) {
          __bf16* o = (__bf16*)qout;
#pragma unroll
          for (int j = 0; j < 4; ++j)
            o[((size_t)(bi*NHEADS + hh)*SEQ + s + j)*HDIM + dd] =
                (__bf16)((acc[m][n][j] + bv) * QSCALE);
        } else {
          __bf16* o = (__bf16*)kout;
#pragma unroll
          for (int j = 0; j < 4; ++j)
            o[((size_t)(bi*NHEADS + hh)*SEQ + s + j)*HDIM + dd] = (__bf16)(acc[m][n][j] + bv);
        }
      } else {
#pragma unroll
        for (int j = 0; j < 4; ++j)
          outf[(size_t)(rowb + j)*DMODEL + colL] = acc[m][n][j] + bv;
      }
    }
  }
}

// Flash attention, 32x32 MFMA, fully in-register softmax (swapped QK^T puts a
// q-row's 16 scores in one lane; P->PV A-frags via cvt_pk + permlane32_swap).
// 8-wave blocks (512 thr) = 2 row-waves(32q) x 4 key-groups (KVBLK=64,
// single-buffered). LDS 65 KB -> 2 blocks/CU = 16 waves/CU; grid 1024 LPT =
// 2x oversubscribed (backfill). Fixed-shift softmax; merge = pure sums.
__global__ __launch_bounds__(512, 4)
void attn_fwd(const unsigned short* __restrict__ qb,
              const unsigned short* __restrict__ kb,
              const unsigned short* __restrict__ vtb,
              const int* __restrict__ ids,
              unsigned short* __restrict__ outb)
{
  const int bx = blockIdx.x;
  const int hb = bx & 31;
  const int qt = 31 - (bx >> 5);        // LPT: longest first
  const int h = hb & 15, bi = hb >> 4;

  const int tid = threadIdx.x, wid = tid >> 6, lane = tid & 63;
  const int grp  = wid >> 1;            // key-quarter group 0..3
  const int wrow = wid & 1;             // row-wave within group
  const int qbase = qt * 64;
  const size_t hoff = (size_t)(bi*NHEADS + h) * SEQ * HDIM;
  const unsigned short* Qh  = qb  + hoff;
  const unsigned short* Kh  = kb  + hoff;
  const unsigned short* Vth = vtb + hoff;   // [d][s]

  __shared__ unsigned short Ks[4][64*64];   // [grp] 32 KiB
  __shared__ unsigned short Vs[4][64*64];   // [grp] 32 KiB
  __shared__ float Lbuf[4][64];             // 1 KiB  -> 65 KiB total

  const int q_ = lane & 31;
  const int hi = lane >> 5;
  const int qg = qbase + wrow*32 + q_;

  // Q B-fragments: col=q, k-dim d = dc*16 + hi*8 + j
  bf16x8 qf[4];
#pragma unroll
  for (int dc = 0; dc < 4; ++dc)
    qf[dc] = *(const bf16x8*)(Qh + (size_t)qg*HDIM + dc*16 + hi*8);

  // staging: group = 128 thr; tile = 512 chunks of 16B; 4 chunks/thread
  const int gt = tid & 127;
  const int grow = gt >> 3;                       // 0..15 (+16i)
  const int gsw  = ((gt & 7) ^ (grow & 7)) * 8;
  __bf16* OB = (grp == 1) ? (__bf16*)Ks :
               (grp == 2) ? (__bf16*)(Ks[2]) : (__bf16*)Vs;  // f32 overlay base

#define STAGE(T) do {                                                          \
    const unsigned short* kbase_ = Kh + (size_t)((T)*64) * HDIM;               \
    const unsigned short* vbase_ = Vth + (T)*64;                               \
    _Pragma("unroll")                                                          \
    for (int i_ = 0; i_ < 4; ++i_) {                                           \
      __builtin_amdgcn_global_load_lds(                                        \
          (gvoid*)(kbase_ + (size_t)(i_*16 + grow)*HDIM + gsw),                \
          (lvoid*)(Ks[grp] + (i_*128 + gt)*8), 16, 0, 0);                      \
      __builtin_amdgcn_global_load_lds(                                        \
          (gvoid*)(vbase_ + (size_t)(i_*16 + grow)*SEQ + gsw),                 \
          (lvoid*)(Vs[grp] + (i_*128 + gt)*8), 16, 0, 0);                      \
    }                                                                          \
  } while (0)

  float lsum = 0.f;
  floatx16 Oacc[2] = {};

  const int nT = qt + 1;
  const int base = nT >> 2, rem = nT & 3;
  const int cnt = base + (grp < rem);
  const int tb  = grp*base + ((grp < rem) ? grp : rem);
  const int Hi  = base + (rem ? 1 : 0);

  if (cnt > 0) STAGE(tb);

  for (int i = 0; i < Hi; ++i) {
    const bool valid = (i < cnt);
    const int t = tb + i;
    const int kb0 = t * 64;
    int pvv = 1;
    if (valid) pvv = ids[bi*SEQ + kb0 + lane];
    asm volatile("s_waitcnt vmcnt(0)" ::: "memory");
    const unsigned long long wm = __ballot(pvv == 0);
    __builtin_amdgcn_s_barrier();
    __builtin_amdgcn_sched_barrier(0);

    if (valid) {
      const bool maskstep = (t == nT - 1) || (wm != 0ull);
#pragma unroll
      for (int H = 0; H < 2; ++H) {
        floatx16 st = {};
        const int kr = H*32 + q_;
        __builtin_amdgcn_s_setprio(1);
#pragma unroll
        for (int dc = 0; dc < 4; ++dc) {
          const int ch = ((dc*2 + hi) ^ (q_ & 7)) * 8;
          bf16x8 kf = *(const bf16x8*)(Ks[grp] + kr*64 + ch);
          st = __builtin_amdgcn_mfma_f32_32x32x16_bf16(kf, qf[dc], st, 0, 0, 0);
        }
        __builtin_amdgcn_s_setprio(0);

        float p[16];
        float ps = 0.f;
        if (!maskstep) {
#pragma unroll
          for (int r = 0; r < 16; ++r) { p[r] = exp2f(st[r]); ps += p[r]; }
        } else {
#pragma unroll
          for (int r = 0; r < 16; ++r) {
            const int crow = (r & 3) + 4*hi + 8*(r >> 2);
            const int kglob = kb0 + H*32 + crow;
            const bool dead = (kglob > qg) || (((wm >> (H*32 + crow)) & 1ull) != 0ull);
            p[r] = dead ? 0.f : exp2f(st[r]);
            ps += p[r];
          }
        }
        lsum += ps;

        // A-frags for slices s = 2H + b via cvt_pk + permlane32_swap
        __builtin_amdgcn_s_setprio(1);
#pragma unroll
        for (int b = 0; b < 2; ++b) {
          unsigned W0 = cvtpk(p[8*b+0], p[8*b+1]);
          unsigned W1 = cvtpk(p[8*b+2], p[8*b+3]);
          unsigned W2 = cvtpk(p[8*b+4], p[8*b+5]);
          unsigned W3 = cvtpk(p[8*b+6], p[8*b+7]);
          uintx2 s02 = __builtin_amdgcn_permlane32_swap(W0, W2, false, false);
          uintx2 s13 = __builtin_amdgcn_permlane32_swap(W1, W3, false, false);
          union { unsigned u[4]; bf16x8 v; } af;
          af.u[0] = s02[0]; af.u[1] = s13[0]; af.u[2] = s02[1]; af.u[3] = s13[1];
          const int s = H*2 + b;
#pragma unroll
          for (int n = 0; n < 2; ++n) {
            const int d = n*32 + q_;
            const int ch = ((s*2 + hi) ^ (d & 7)) * 8;
            bf16x8 vf = *(const bf16x8*)(Vs[grp] + d*64 + ch);
            Oacc[n] = __builtin_amdgcn_mfma_f32_32x32x16_bf16(af.v, vf, Oacc[n], 0, 0, 0);
          }
        }
        __builtin_amdgcn_s_setprio(0);
      }
    }
    __builtin_amdgcn_s_barrier();               // compute done -> restage safe
    if (i + 1 < cnt) STAGE(t + 1);
  }
#undef STAGE

  // per-lane l covers this (group, hi) key subset; sum hi-halves
  float lt = lsum + __shfl_xor(lsum, 32);

  // merge: groups 1-3 write f32 numerators to LDS overlays; all write Lbuf
  float* B1 = (float*)Ks;
  float* B2 = B1 + 4096;
  float* B3 = (float*)Vs;
  float* OBf = (grp == 1) ? B1 : (grp == 2) ? B2 : B3;
  if (grp >= 1) {
#pragma unroll
    for (int r = 0; r < 16; ++r) {
      const int row = wrow*32 + (r & 3) + 4*hi + 8*(r >> 2);
      OBf[row*64 + q_]      = Oacc[0][r];
      OBf[row*64 + 32 + q_] = Oacc[1][r];
    }
  }
  if (hi == 0) Lbuf[grp][wrow*32 + q_] = lt;
  __syncthreads();

  if (grp == 0) {
#pragma unroll
    for (int r = 0; r < 16; ++r) {
      const int row = wrow*32 + (r & 3) + 4*hi + 8*(r >> 2);
      const int rq = row & 63;
      const float den = Lbuf[0][rq] + Lbuf[1][rq] + Lbuf[2][rq] + Lbuf[3][rq];
      const float inv = 1.f / den;
      const float o0 = Oacc[0][r] + B1[row*64 + q_] + B2[row*64 + q_] + B3[row*64 + q_];
      const float o1 = Oacc[1][r] + B1[row*64 + 32 + q_] + B2[row*64 + 32 + q_] + B3[row*64 + 32 + q_];
      const size_t grow_ = (size_t)(bi*SEQ + qbase + row);
      ((__bf16*)outb)[grow_*DMODEL + h*HDIM + q_]      = (__bf16)(o0 * inv);
      ((__bf16*)outb)[grow_*DMODEL + h*HDIM + 32 + q_] = (__bf16)(o1 * inv);
    }
  }
}

extern "C" void kernel_launch(void* const* d_in, const int* in_sizes, int n_in,
                              void* d_out, int out_size, void* d_ws, size_t ws_size,
                              hipStream_t stream)
{
  const float* x  = (const float*)d_in[0];
  const int*   ids= (const int*)d_in[1];
  const float* Wq = (const float*)d_in[2];
  const float* bq = (const float*)d_in[3];
  const float* Wk = (const float*)d_in[4];
  const float* bk = (const float*)d_in[5];
  const float* Wv = (const float*)d_in[6];
  const float* bv = (const float*)d_in[7];
  const float* Wo = (const float*)d_in[8];
  const float* bo = (const float*)d_in[9];
  float* out = (float*)d_out;

  char* ws = (char*)d_ws;
  unsigned short* xb   = (unsigned short*)(ws);
  unsigned short* wqb  = (unsigned short*)(ws + ( 8u<<20));
  unsigned short* wkb  = (unsigned short*)(ws + (10u<<20));
  unsigned short* wvb  = (unsigned short*)(ws + (12u<<20));
  unsigned short* wob  = (unsigned short*)(ws + (14u<<20));
  unsigned short* qbuf = (unsigned short*)(ws + (16u<<20));
  unsigned short* kbuf = (unsigned short*)(ws + (24u<<20));
  unsigned short* vbuf = (unsigned short*)(ws + (32u<<20));  // [b,h,d,s]
  unsigned short* abuf = (unsigned short*)(ws + (40u<<20));

  cast_all<<<8192, 256, 0, stream>>>(x, Wq, Wk, Wv, Wo,
                                     (__bf16*)xb, (__bf16*)wqb, (__bf16*)wkb,
                                     (__bf16*)wvb, (__bf16*)wob);

  gemm_nt<0><<<768, 256, 0, stream>>>(xb, wqb, wkb, wvb, bq, bk, bv,
                                      qbuf, kbuf, vbuf, nullptr);

  attn_fwd<<<1024, 512, 0, stream>>>(qbuf, kbuf, vbuf, ids, abuf);

  gemm_nt<1><<<256, 256, 0, stream>>>(abuf, wob, wob, wob, bo, bo, bo,
                                      nullptr, nullptr, nullptr, out);
}

// Round 15
// 111.833 us; speedup vs baseline: 1.2070x; 1.2070x over previous
//
#include <hip/hip_runtime.h>

#define DMODEL 1024
#define NHEADS 16
#define HDIM   64
#define BATCH  2
#define SEQ    2048
#define MROWS  (BATCH*SEQ)

typedef __bf16 bf16x8 __attribute__((ext_vector_type(8)));
typedef __bf16 bf16x4 __attribute__((ext_vector_type(4)));
typedef float floatx4 __attribute__((ext_vector_type(4)));

typedef const __attribute__((address_space(1))) void gvoid;
typedef __attribute__((address_space(3))) void lvoid;

template<bool V> struct ICb { static constexpr bool value = V; };

// Q pre-scale: 1/sqrt(64) * log2(e), folded into the QKV GEMM epilogue.
#define QSCALE 0.18033688011112042f

// Single cast kernel: x (1048576 float4) then Wq/Wk/Wv/Wo (262144 float4 each).
__global__ void cast_all(const float* __restrict__ x,
                         const float* __restrict__ wq, const float* __restrict__ wk,
                         const float* __restrict__ wv, const float* __restrict__ wo,
                         __bf16* __restrict__ xb, __bf16* __restrict__ wqb,
                         __bf16* __restrict__ wkb, __bf16* __restrict__ wvb,
                         __bf16* __restrict__ wob)
{
  const int i = blockIdx.x * 256 + threadIdx.x;
  const float* s; __bf16* o; int off;
  if (i < MROWS*DMODEL/4) { s = x; o = xb; off = i; }
  else {
    const int r = i - MROWS*DMODEL/4;
    const int w = r >> 18;
    off = r & 262143;
    s = (w == 0) ? wq : (w == 1) ? wk : (w == 2) ? wv : wo;
    o = (w == 0) ? wqb : (w == 1) ? wkb : (w == 2) ? wvb : wob;
  }
  const float4 f = ((const float4*)s)[off];
  bf16x4 v = {(__bf16)f.x, (__bf16)f.y, (__bf16)f.z, (__bf16)f.w};
  *(bf16x4*)(o + off*4) = v;
}

// NT GEMM: double-buffered gload_lds + vmcnt(4), XCD-chunk swizzle, setprio.
// MODE 0: fused QKV; q pre-scaled by QSCALE -> [b,h,s,d], k -> [b,h,s,d],
//         v -> [b,h,d,s]. MODE 1: fp32 row-major (output projection).
template<int MODE>
__global__ __launch_bounds__(256, 3)
void gemm_nt(const unsigned short* __restrict__ A,
             const unsigned short* __restrict__ W0,
             const unsigned short* __restrict__ W1,
             const unsigned short* __restrict__ W2,
             const float* __restrict__ b0,
             const float* __restrict__ b1,
             const float* __restrict__ b2,
             unsigned short* __restrict__ qout,
             unsigned short* __restrict__ kout,
             unsigned short* __restrict__ vout,
             float* __restrict__ outf)
{
  const int K = DMODEL;
  __shared__ unsigned short As[2][128*32];
  __shared__ unsigned short Bs[2][128*32];
  const int tid  = threadIdx.x;
  const int wid  = tid >> 6;
  const int lane = tid & 63;

  const int lin = blockIdx.x;
  const int wg  = (MODE == 0) ? ((lin & 7)*96 + (lin >> 3))
                              : ((lin & 7)*32 + (lin >> 3));
  const int bx  = (MODE == 0) ? (wg % 24) : (wg & 7);
  const int by  = (MODE == 0) ? (wg / 24) : (wg >> 3);
  const int brow = by * 128;
  const int bcol = bx * 128;
  const int wr = (wid >> 1) * 64;
  const int wc = (wid & 1) * 64;

  int which = 0;
  const unsigned short* Bw = W0;
  const float* bias = b0;
  int bcolL = bcol;
  if (MODE == 0) {
    which = bcol >> 10;
    Bw   = which == 0 ? W0 : which == 1 ? W1 : W2;
    bias = which == 0 ? b0 : which == 1 ? b1 : b2;
    bcolL = bcol & 1023;
  }

  floatx4 acc[4][4] = {};

  const int sr = wid*16 + (lane >> 2);
  const int sc = (lane & 3) * 8;
  const int fr = lane & 15;
  const int fk = (lane >> 4) * 8;

#define GSTAGE(KT, B) do {                                                     \
    _Pragma("unroll")                                                          \
    for (int i_ = 0; i_ < 2; ++i_) {                                           \
      __builtin_amdgcn_global_load_lds(                                        \
          (gvoid*)(A + (size_t)(brow + i_*64 + sr)*K + (KT) + sc),             \
          (lvoid*)(As[B] + i_*2048 + wid*512), 16, 0, 0);                      \
      __builtin_amdgcn_global_load_lds(                                        \
          (gvoid*)(Bw + (size_t)(bcolL + i_*64 + sr)*K + (KT) + sc),           \
          (lvoid*)(Bs[B] + i_*2048 + wid*512), 16, 0, 0);                      \
    }                                                                          \
  } while (0)

  GSTAGE(0, 0);

  for (int kt = 0; kt < K; kt += 32) {
    const int cur = (kt >> 5) & 1;
    if (kt + 32 < K) {
      GSTAGE(kt + 32, cur ^ 1);
      asm volatile("s_waitcnt vmcnt(4)" ::: "memory");
    } else {
      asm volatile("s_waitcnt vmcnt(0)" ::: "memory");
    }
    __builtin_amdgcn_s_barrier();
    __builtin_amdgcn_sched_barrier(0);

    bf16x8 af[4], bfv[4];
#pragma unroll
    for (int m = 0; m < 4; ++m)
      af[m] = *(const bf16x8*)(As[cur] + (wr + m*16 + fr)*32 + fk);
#pragma unroll
    for (int n = 0; n < 4; ++n)
      bfv[n] = *(const bf16x8*)(Bs[cur] + (wc + n*16 + fr)*32 + fk);
    __builtin_amdgcn_s_setprio(1);
#pragma unroll
    for (int m = 0; m < 4; ++m)
#pragma unroll
      for (int n = 0; n < 4; ++n)
        acc[m][n] = __builtin_amdgcn_mfma_f32_16x16x32_bf16(af[m], bfv[n], acc[m][n], 0, 0, 0);
    __builtin_amdgcn_s_setprio(0);
    __builtin_amdgcn_s_barrier();
  }
#undef GSTAGE

  const int er = (lane >> 4) * 4;
  const int ec = lane & 15;
#pragma unroll
  for (int m = 0; m < 4; ++m) {
#pragma unroll
    for (int n = 0; n < 4; ++n) {
      const int colL = bcolL + wc + n*16 + ec;
      const float bv = bias[colL];
      const int rowb = brow + wr + m*16 + er;
      if (MODE == 0) {
        const int bi = rowb >> 11, s = rowb & 2047;
        const int hh = colL >> 6, dd = colL & 63;
        if (which == 2) {
          bf16x4 v4 = {(__bf16)(acc[m][n][0] + bv), (__bf16)(acc[m][n][1] + bv),
                       (__bf16)(acc[m][n][2] + bv), (__bf16)(acc[m][n][3] + bv)};
          *(bf16x4*)((__bf16*)vout + ((size_t)(bi*NHEADS + hh)*HDIM + dd)*SEQ + s) = v4;
        } else if (which == 0) {
          __bf16* o = (__bf16*)qout;
#pragma unroll
          for (int j = 0; j < 4; ++j)
            o[((size_t)(bi*NHEADS + hh)*SEQ + s + j)*HDIM + dd] =
                (__bf16)((acc[m][n][j] + bv) * QSCALE);
        } else {
          __bf16* o = (__bf16*)kout;
#pragma unroll
          for (int j = 0; j < 4; ++j)
            o[((size_t)(bi*NHEADS + hh)*SEQ + s + j)*HDIM + dd] = (__bf16)(acc[m][n][j] + bv);
        }
      } else {
#pragma unroll
        for (int j = 0; j < 4; ++j)
          outf[(size_t)(rowb + j)*DMODEL + colL] = acc[m][n][j] + bv;
      }
    }
  }
}

// Flash attention, fixed-shift softmax, KEY-SPLIT form (r11, best measured:
// 50.9 us, occ 33%). 8-wave blocks (512 thr); waves 0-3 process key-tiles
// [0,h0), waves 4-7 process [h0,nT) of the SAME 64 q-rows, each group with
// its own double-buffered K/V pipeline. LDS exactly 80 KiB -> 2 blocks/CU =
// 16 waves/CU. Grid 1024 = 2x oversubscribed, LPT (qt descending) backfill.
// Fixed-shift merge: add O-numerators + l via LDS (reuse Ps).
__global__ __launch_bounds__(512, 4)
void attn_fwd(const unsigned short* __restrict__ qb,
              const unsigned short* __restrict__ kb,
              const unsigned short* __restrict__ vtb,
              const int* __restrict__ ids,
              unsigned short* __restrict__ outb)
{
  const int bx = blockIdx.x;
  const int hb = bx & 31;
  const int qt = 31 - (bx >> 5);        // LPT: longest blocks dispatch first
  const int h = hb & 15, bi = hb >> 4;

  const int tid = threadIdx.x, wid = tid >> 6, lane = tid & 63;
  const int grp  = wid >> 2;            // key-half group
  const int wid4 = wid & 3;             // row-group within block
  const int qbase = qt * 64;
  const size_t hoff = (size_t)(bi*NHEADS + h) * SEQ * HDIM;
  const unsigned short* Qh  = qb  + hoff;
  const unsigned short* Kh  = kb  + hoff;
  const unsigned short* Vth = vtb + hoff;   // [d][s]

  __shared__ unsigned short Ks[2][2][64*64];  // [grp][buf] 32 KiB
  __shared__ unsigned short Vs[2][2][64*64];  // 32 KiB
  __shared__ unsigned short Ps[8][16*64];     // 16 KiB -> 80 KiB total
  float* LOf = (float*)Ps;   // post-loop: 64x64 f32 merge buffer (16 KiB)
  float* Ll  = (float*)Ks;   // post-loop: 64 f32 row-sums

  const int q_   = lane & 15;
  const int hi4  = lane >> 4;
  const int koff = hi4 * 4;
  const int qg = qbase + wid4*16 + q_;

  bf16x8 qf[2];
#pragma unroll
  for (int c = 0; c < 2; ++c)
    qf[c] = *(const bf16x8*)(Qh + (size_t)qg*HDIM + c*32 + hi4*8);

  // staging: per group, tile = 512 16B-chunks; group-thread covers gt, gt+256
  const int gt = tid & 255;
  const int r0 = gt >> 3;                         // 0..31 (+32)
  const int sw = ((gt & 7) ^ (r0 & 7)) * 8;
  unsigned short* Pw = Ps[wid];

#define STAGE(T, B) do {                                                       \
    const unsigned short* kbase_ = Kh + (size_t)((T)*64) * HDIM;               \
    const unsigned short* vbase_ = Vth + (T)*64;                               \
    __builtin_amdgcn_global_load_lds((gvoid*)(kbase_ + r0*64 + sw),            \
                                     (lvoid*)(Ks[grp][B] + gt*8), 16, 0, 0);   \
    __builtin_amdgcn_global_load_lds((gvoid*)(kbase_ + (r0+32)*64 + sw),       \
                                     (lvoid*)(Ks[grp][B] + (gt+256)*8), 16, 0, 0);\
    __builtin_amdgcn_global_load_lds((gvoid*)(vbase_ + (size_t)r0*SEQ + sw),   \
                                     (lvoid*)(Vs[grp][B] + gt*8), 16, 0, 0);   \
    __builtin_amdgcn_global_load_lds((gvoid*)(vbase_ + (size_t)(r0+32)*SEQ + sw),\
                                     (lvoid*)(Vs[grp][B] + (gt+256)*8), 16, 0, 0);\
  } while (0)

  float lsum = 0.f;
  floatx4 Oacc[4] = {};

  auto step = [&](auto Mc, int kb0, int bufc, unsigned long long wm) {
    constexpr bool MASKED = decltype(Mc)::value;

    floatx4 st[4];
    __builtin_amdgcn_s_setprio(1);
#pragma unroll
    for (int t = 0; t < 4; ++t) {
      st[t] = (floatx4){0.f, 0.f, 0.f, 0.f};
      const int kr = t*16 + q_;
#pragma unroll
      for (int c = 0; c < 2; ++c) {
        const int cd = ((c*4 + hi4) ^ (kr & 7)) * 8;
        bf16x8 kf = *(const bf16x8*)(Ks[grp][bufc] + kr*64 + cd);
        st[t] = __builtin_amdgcn_mfma_f32_16x16x32_bf16(kf, qf[c], st[t], 0, 0, 0);
      }
    }
    __builtin_amdgcn_s_setprio(0);

    float ps = 0.f;
#pragma unroll
    for (int t = 0; t < 4; ++t) {
      float p[4];
#pragma unroll
      for (int r = 0; r < 4; ++r) {
        float pv = exp2f(st[t][r]);               // Q pre-scaled
        if (MASKED) {
          const int ko = t*16 + koff + r;
          const bool dead = ((kb0 + ko) > qg) || (((wm >> ko) & 1ull) != 0ull);
          pv = dead ? 0.f : pv;
        }
        p[r] = pv;
        ps += pv;
      }
      bf16x4 pk = {(__bf16)p[0], (__bf16)p[1], (__bf16)p[2], (__bf16)p[3]};
      const int ko = t*16 + koff;
      *(bf16x4*)(Pw + q_*64 + (((ko >> 3) ^ (q_ & 7)) * 8) + (ko & 7)) = pk;
    }
    lsum += ps;

    __builtin_amdgcn_s_setprio(1);
#pragma unroll
    for (int cp = 0; cp < 2; ++cp) {
      const int ko = cp*32 + hi4*8;
      bf16x8 pf = *(const bf16x8*)(Pw + q_*64 + (((ko >> 3) ^ (q_ & 7)) * 8));
#pragma unroll
      for (int n = 0; n < 4; ++n) {
        const int d = n*16 + q_;
        const int cd = ((cp*4 + hi4) ^ (d & 7)) * 8;
        bf16x8 vf = *(const bf16x8*)(Vs[grp][bufc] + d*64 + cd);
        Oacc[n] = __builtin_amdgcn_mfma_f32_16x16x32_bf16(pf, vf, Oacc[n], 0, 0, 0);
      }
    }
    __builtin_amdgcn_s_setprio(0);
  };

  const int nT = qt + 1;
  const int h0 = (nT + 1) >> 1;               // group0 tile count = H
  const int cnt = (grp == 0) ? h0 : nT - h0;  // this group's tile count
  const int tb  = (grp == 0) ? 0 : h0;        // this group's first tile
  const int H = h0;

  if (cnt > 0) STAGE(tb, 0);

  for (int i = 0; i < H; ++i) {
    const bool valid = (i < cnt);
    const int t = tb + i;
    const int kb0 = t * 64;
    int pv = 1;
    if (valid) pv = ids[bi*SEQ + kb0 + lane];
    if (i + 1 < cnt) {
      STAGE(t + 1, (i + 1) & 1);
      asm volatile("s_waitcnt vmcnt(4)" ::: "memory");
    } else {
      asm volatile("s_waitcnt vmcnt(0)" ::: "memory");
    }
    const unsigned long long wm = __ballot(pv == 0);
    __builtin_amdgcn_s_barrier();
    __builtin_amdgcn_sched_barrier(0);

    if (valid) {
      const int bufc = i & 1;
      if ((t != nT - 1) && wm == 0ull) step(ICb<false>{}, kb0, bufc, 0ull);
      else                             step(ICb<true >{}, kb0, bufc, wm);
    }
    __builtin_amdgcn_s_barrier();
  }
#undef STAGE

  // per-group l reduce (lane holds row q_'s partial over its key subset)
  float lt = lsum + __shfl_xor(lsum, 16);
  lt += __shfl_xor(lt, 32);

  // merge: group1 -> LDS (f32 numerators + l), group0 adds + normalizes
  if (grp == 1) {
#pragma unroll
    for (int r = 0; r < 4; ++r)
#pragma unroll
      for (int n = 0; n < 4; ++n)
        LOf[(wid4*16 + koff + r)*64 + n*16 + q_] = Oacc[n][r];
    if (hi4 == 0) Ll[wid4*16 + q_] = lt;
  }
  __syncthreads();
  if (grp == 0) {
#pragma unroll
    for (int r = 0; r < 4; ++r) {
      const int rloc = wid4*16 + koff + r;
      const float inv = 1.f / (__shfl(lt, koff + r) + Ll[rloc]);
      const int row = bi*SEQ + qbase + rloc;
#pragma unroll
      for (int n = 0; n < 4; ++n) {
        const float o = Oacc[n][r] + LOf[rloc*64 + n*16 + q_];
        ((__bf16*)outb)[(size_t)row*DMODEL + h*HDIM + n*16 + q_] = (__bf16)(o * inv);
      }
    }
  }
}

extern "C" void kernel_launch(void* const* d_in, const int* in_sizes, int n_in,
                              void* d_out, int out_size, void* d_ws, size_t ws_size,
                              hipStream_t stream)
{
  const float* x  = (const float*)d_in[0];
  const int*   ids= (const int*)d_in[1];
  const float* Wq = (const float*)d_in[2];
  const float* bq = (const float*)d_in[3];
  const float* Wk = (const float*)d_in[4];
  const float* bk = (const float*)d_in[5];
  const float* Wv = (const float*)d_in[6];
  const float* bv = (const float*)d_in[7];
  const float* Wo = (const float*)d_in[8];
  const float* bo = (const float*)d_in[9];
  float* out = (float*)d_out;

  char* ws = (char*)d_ws;
  unsigned short* xb   = (unsigned short*)(ws);
  unsigned short* wqb  = (unsigned short*)(ws + ( 8u<<20));
  unsigned short* wkb  = (unsigned short*)(ws + (10u<<20));
  unsigned short* wvb  = (unsigned short*)(ws + (12u<<20));
  unsigned short* wob  = (unsigned short*)(ws + (14u<<20));
  unsigned short* qbuf = (unsigned short*)(ws + (16u<<20));
  unsigned short* kbuf = (unsigned short*)(ws + (24u<<20));
  unsigned short* vbuf = (unsigned short*)(ws + (32u<<20));  // [b,h,d,s]
  unsigned short* abuf = (unsigned short*)(ws + (40u<<20));

  cast_all<<<8192, 256, 0, stream>>>(x, Wq, Wk, Wv, Wo,
                                     (__bf16*)xb, (__bf16*)wqb, (__bf16*)wkb,
                                     (__bf16*)wvb, (__bf16*)wob);

  gemm_nt<0><<<768, 256, 0, stream>>>(xb, wqb, wkb, wvb, bq, bk, bv,
                                      qbuf, kbuf, vbuf, nullptr);

  attn_fwd<<<1024, 512, 0, stream>>>(qbuf, kbuf, vbuf, ids, abuf);

  gemm_nt<1><<<256, 256, 0, stream>>>(abuf, wob, wob, wob, bo, bo, bo,
                                      nullptr, nullptr, nullptr, out);
}

// Round 16
// 111.709 us; speedup vs baseline: 1.2084x; 1.0011x over previous
//
#include <hip/hip_runtime.h>

#define DMODEL 1024
#define NHEADS 16
#define HDIM   64
#define BATCH  2
#define SEQ    2048
#define MROWS  (BATCH*SEQ)

typedef __bf16 bf16x8 __attribute__((ext_vector_type(8)));
typedef __bf16 bf16x4 __attribute__((ext_vector_type(4)));
typedef float floatx4 __attribute__((ext_vector_type(4)));

typedef const __attribute__((address_space(1))) void gvoid;
typedef __attribute__((address_space(3))) void lvoid;

template<bool V> struct ICb { static constexpr bool value = V; };

// Q pre-scale: 1/sqrt(64) * log2(e), folded into the QKV GEMM epilogue.
#define QSCALE 0.18033688011112042f

// Single cast kernel: x (1048576 float4) then Wq/Wk/Wv/Wo (262144 float4 each).
__global__ void cast_all(const float* __restrict__ x,
                         const float* __restrict__ wq, const float* __restrict__ wk,
                         const float* __restrict__ wv, const float* __restrict__ wo,
                         __bf16* __restrict__ xb, __bf16* __restrict__ wqb,
                         __bf16* __restrict__ wkb, __bf16* __restrict__ wvb,
                         __bf16* __restrict__ wob)
{
  const int i = blockIdx.x * 256 + threadIdx.x;
  const float* s; __bf16* o; int off;
  if (i < MROWS*DMODEL/4) { s = x; o = xb; off = i; }
  else {
    const int r = i - MROWS*DMODEL/4;
    const int w = r >> 18;
    off = r & 262143;
    s = (w == 0) ? wq : (w == 1) ? wk : (w == 2) ? wv : wo;
    o = (w == 0) ? wqb : (w == 1) ? wkb : (w == 2) ? wvb : wob;
  }
  const float4 f = ((const float4*)s)[off];
  bf16x4 v = {(__bf16)f.x, (__bf16)f.y, (__bf16)f.z, (__bf16)f.w};
  *(bf16x4*)(o + off*4) = v;
}

// NT GEMM: double-buffered gload_lds + vmcnt(4), XCD-chunk swizzle, setprio.
template<int MODE>
__global__ __launch_bounds__(256, 3)
void gemm_nt(const unsigned short* __restrict__ A,
             const unsigned short* __restrict__ W0,
             const unsigned short* __restrict__ W1,
             const unsigned short* __restrict__ W2,
             const float* __restrict__ b0,
             const float* __restrict__ b1,
             const float* __restrict__ b2,
             unsigned short* __restrict__ qout,
             unsigned short* __restrict__ kout,
             unsigned short* __restrict__ vout,
             float* __restrict__ outf)
{
  const int K = DMODEL;
  __shared__ unsigned short As[2][128*32];
  __shared__ unsigned short Bs[2][128*32];
  const int tid  = threadIdx.x;
  const int wid  = tid >> 6;
  const int lane = tid & 63;

  const int lin = blockIdx.x;
  const int wg  = (MODE == 0) ? ((lin & 7)*96 + (lin >> 3))
                              : ((lin & 7)*32 + (lin >> 3));
  const int bx  = (MODE == 0) ? (wg % 24) : (wg & 7);
  const int by  = (MODE == 0) ? (wg / 24) : (wg >> 3);
  const int brow = by * 128;
  const int bcol = bx * 128;
  const int wr = (wid >> 1) * 64;
  const int wc = (wid & 1) * 64;

  int which = 0;
  const unsigned short* Bw = W0;
  const float* bias = b0;
  int bcolL = bcol;
  if (MODE == 0) {
    which = bcol >> 10;
    Bw   = which == 0 ? W0 : which == 1 ? W1 : W2;
    bias = which == 0 ? b0 : which == 1 ? b1 : b2;
    bcolL = bcol & 1023;
  }

  floatx4 acc[4][4] = {};

  const int sr = wid*16 + (lane >> 2);
  const int sc = (lane & 3) * 8;
  const int fr = lane & 15;
  const int fk = (lane >> 4) * 8;

#define GSTAGE(KT, B) do {                                                     \
    _Pragma("unroll")                                                          \
    for (int i_ = 0; i_ < 2; ++i_) {                                           \
      __builtin_amdgcn_global_load_lds(                                        \
          (gvoid*)(A + (size_t)(brow + i_*64 + sr)*K + (KT) + sc),             \
          (lvoid*)(As[B] + i_*2048 + wid*512), 16, 0, 0);                      \
      __builtin_amdgcn_global_load_lds(                                        \
          (gvoid*)(Bw + (size_t)(bcolL + i_*64 + sr)*K + (KT) + sc),           \
          (lvoid*)(Bs[B] + i_*2048 + wid*512), 16, 0, 0);                      \
    }                                                                          \
  } while (0)

  GSTAGE(0, 0);

  for (int kt = 0; kt < K; kt += 32) {
    const int cur = (kt >> 5) & 1;
    if (kt + 32 < K) {
      GSTAGE(kt + 32, cur ^ 1);
      asm volatile("s_waitcnt vmcnt(4)" ::: "memory");
    } else {
      asm volatile("s_waitcnt vmcnt(0)" ::: "memory");
    }
    __builtin_amdgcn_s_barrier();
    __builtin_amdgcn_sched_barrier(0);

    bf16x8 af[4], bfv[4];
#pragma unroll
    for (int m = 0; m < 4; ++m)
      af[m] = *(const bf16x8*)(As[cur] + (wr + m*16 + fr)*32 + fk);
#pragma unroll
    for (int n = 0; n < 4; ++n)
      bfv[n] = *(const bf16x8*)(Bs[cur] + (wc + n*16 + fr)*32 + fk);
    __builtin_amdgcn_s_setprio(1);
#pragma unroll
    for (int m = 0; m < 4; ++m)
#pragma unroll
      for (int n = 0; n < 4; ++n)
        acc[m][n] = __builtin_amdgcn_mfma_f32_16x16x32_bf16(af[m], bfv[n], acc[m][n], 0, 0, 0);
    __builtin_amdgcn_s_setprio(0);
    __builtin_amdgcn_s_barrier();
  }
#undef GSTAGE

  const int er = (lane >> 4) * 4;
  const int ec = lane & 15;
#pragma unroll
  for (int m = 0; m < 4; ++m) {
#pragma unroll
    for (int n = 0; n < 4; ++n) {
      const int colL = bcolL + wc + n*16 + ec;
      const float bv = bias[colL];
      const int rowb = brow + wr + m*16 + er;
      if (MODE == 0) {
        const int bi = rowb >> 11, s = rowb & 2047;
        const int hh = colL >> 6, dd = colL & 63;
        if (which == 2) {
          bf16x4 v4 = {(__bf16)(acc[m][n][0] + bv), (__bf16)(acc[m][n][1] + bv),
                       (__bf16)(acc[m][n][2] + bv), (__bf16)(acc[m][n][3] + bv)};
          *(bf16x4*)((__bf16*)vout + ((size_t)(bi*NHEADS + hh)*HDIM + dd)*SEQ + s) = v4;
        } else if (which == 0) {
          __bf16* o = (__bf16*)qout;
#pragma unroll
          for (int j = 0; j < 4; ++j)
            o[((size_t)(bi*NHEADS + hh)*SEQ + s + j)*HDIM + dd] =
                (__bf16)((acc[m][n][j] + bv) * QSCALE);
        } else {
          __bf16* o = (__bf16*)kout;
#pragma unroll
          for (int j = 0; j < 4; ++j)
            o[((size_t)(bi*NHEADS + hh)*SEQ + s + j)*HDIM + dd] = (__bf16)(acc[m][n][j] + bv);
        }
      } else {
#pragma unroll
        for (int j = 0; j < 4; ++j)
          outf[(size_t)(rowb + j)*DMODEL + colL] = acc[m][n][j] + bv;
      }
    }
  }
}

// Flash attention, fixed-shift softmax, KEY-SPLIT + PAIRED form:
// 8-wave blocks (512 thr); waves 0-3 / 4-7 split the key range of the SAME
// 64 q-rows, each group double-buffered. Each block processes q-tiles
// (pr, 31-pr) sequentially -> EVERY block exactly 17 group-steps. Grid
// (32,16) = 512 blocks = exactly 2/CU (80 KiB LDS), all resident, uniform
// -> sustained 16 waves/CU, no backfill, no tail. Fixed-shift merge via LDS.
__global__ __launch_bounds__(512, 4)
void attn_fwd(const unsigned short* __restrict__ qb,
              const unsigned short* __restrict__ kb,
              const unsigned short* __restrict__ vtb,
              const int* __restrict__ ids,
              unsigned short* __restrict__ outb)
{
  const int hb = blockIdx.x;
  const int pr = blockIdx.y;
  const int h = hb & 15, bi = hb >> 4;

  const int tid = threadIdx.x, wid = tid >> 6, lane = tid & 63;
  const int grp  = wid >> 2;            // key-half group
  const int wid4 = wid & 3;             // row-group within block
  const size_t hoff = (size_t)(bi*NHEADS + h) * SEQ * HDIM;
  const unsigned short* Qh  = qb  + hoff;
  const unsigned short* Kh  = kb  + hoff;
  const unsigned short* Vth = vtb + hoff;   // [d][s]

  __shared__ unsigned short Ks[2][2][64*64];  // [grp][buf] 32 KiB
  __shared__ unsigned short Vs[2][2][64*64];  // 32 KiB
  __shared__ unsigned short Ps[8][16*64];     // 16 KiB -> 80 KiB total
  float* LOf = (float*)Ps;   // post-loop: 64x64 f32 merge buffer (16 KiB)
  float* Ll  = (float*)Ks;   // post-loop: 64 f32 row-sums

  const int q_   = lane & 15;
  const int hi4  = lane >> 4;
  const int koff = hi4 * 4;

  // staging: per group, tile = 512 16B-chunks; group-thread covers gt, gt+256
  const int gt = tid & 255;
  const int r0 = gt >> 3;                         // 0..31 (+32)
  const int sw = ((gt & 7) ^ (r0 & 7)) * 8;
  unsigned short* Pw = Ps[wid];

#define STAGE(T, B) do {                                                       \
    const unsigned short* kbase_ = Kh + (size_t)((T)*64) * HDIM;               \
    const unsigned short* vbase_ = Vth + (T)*64;                               \
    __builtin_amdgcn_global_load_lds((gvoid*)(kbase_ + r0*64 + sw),            \
                                     (lvoid*)(Ks[grp][B] + gt*8), 16, 0, 0);   \
    __builtin_amdgcn_global_load_lds((gvoid*)(kbase_ + (r0+32)*64 + sw),       \
                                     (lvoid*)(Ks[grp][B] + (gt+256)*8), 16, 0, 0);\
    __builtin_amdgcn_global_load_lds((gvoid*)(vbase_ + (size_t)r0*SEQ + sw),   \
                                     (lvoid*)(Vs[grp][B] + gt*8), 16, 0, 0);   \
    __builtin_amdgcn_global_load_lds((gvoid*)(vbase_ + (size_t)(r0+32)*SEQ + sw),\
                                     (lvoid*)(Vs[grp][B] + (gt+256)*8), 16, 0, 0);\
  } while (0)

  for (int half = 0; half < 2; ++half) {
    const int qt = half ? 31 - pr : pr;
    const int qbase = qt * 64;
    const int qg = qbase + wid4*16 + q_;

    bf16x8 qf[2];
#pragma unroll
    for (int c = 0; c < 2; ++c)
      qf[c] = *(const bf16x8*)(Qh + (size_t)qg*HDIM + c*32 + hi4*8);

    float lsum = 0.f;
    floatx4 Oacc[4] = {};

    auto step = [&](auto Mc, int kb0, int bufc, unsigned long long wm) {
      constexpr bool MASKED = decltype(Mc)::value;

      floatx4 st[4];
      __builtin_amdgcn_s_setprio(1);
#pragma unroll
      for (int t = 0; t < 4; ++t) {
        st[t] = (floatx4){0.f, 0.f, 0.f, 0.f};
        const int kr = t*16 + q_;
#pragma unroll
        for (int c = 0; c < 2; ++c) {
          const int cd = ((c*4 + hi4) ^ (kr & 7)) * 8;
          bf16x8 kf = *(const bf16x8*)(Ks[grp][bufc] + kr*64 + cd);
          st[t] = __builtin_amdgcn_mfma_f32_16x16x32_bf16(kf, qf[c], st[t], 0, 0, 0);
        }
      }
      __builtin_amdgcn_s_setprio(0);

      float ps = 0.f;
#pragma unroll
      for (int t = 0; t < 4; ++t) {
        float p[4];
#pragma unroll
        for (int r = 0; r < 4; ++r) {
          float pv = exp2f(st[t][r]);               // Q pre-scaled
          if (MASKED) {
            const int ko = t*16 + koff + r;
            const bool dead = ((kb0 + ko) > qg) || (((wm >> ko) & 1ull) != 0ull);
            pv = dead ? 0.f : pv;
          }
          p[r] = pv;
          ps += pv;
        }
        bf16x4 pk = {(__bf16)p[0], (__bf16)p[1], (__bf16)p[2], (__bf16)p[3]};
        const int ko = t*16 + koff;
        *(bf16x4*)(Pw + q_*64 + (((ko >> 3) ^ (q_ & 7)) * 8) + (ko & 7)) = pk;
      }
      lsum += ps;

      __builtin_amdgcn_s_setprio(1);
#pragma unroll
      for (int cp = 0; cp < 2; ++cp) {
        const int ko = cp*32 + hi4*8;
        bf16x8 pf = *(const bf16x8*)(Pw + q_*64 + (((ko >> 3) ^ (q_ & 7)) * 8));
#pragma unroll
        for (int n = 0; n < 4; ++n) {
          const int d = n*16 + q_;
          const int cd = ((cp*4 + hi4) ^ (d & 7)) * 8;
          bf16x8 vf = *(const bf16x8*)(Vs[grp][bufc] + d*64 + cd);
          Oacc[n] = __builtin_amdgcn_mfma_f32_16x16x32_bf16(pf, vf, Oacc[n], 0, 0, 0);
        }
      }
      __builtin_amdgcn_s_setprio(0);
    };

    const int nT = qt + 1;
    const int h0 = (nT + 1) >> 1;               // group0 tile count = H
    const int cnt = (grp == 0) ? h0 : nT - h0;  // this group's tile count
    const int tb  = (grp == 0) ? 0 : h0;        // this group's first tile

    if (cnt > 0) STAGE(tb, 0);

    for (int i = 0; i < h0; ++i) {
      const bool valid = (i < cnt);
      const int t = tb + i;
      const int kb0 = t * 64;
      int pv = 1;
      if (valid) pv = ids[bi*SEQ + kb0 + lane];
      if (i + 1 < cnt) {
        STAGE(t + 1, (i + 1) & 1);
        asm volatile("s_waitcnt vmcnt(4)" ::: "memory");
      } else {
        asm volatile("s_waitcnt vmcnt(0)" ::: "memory");
      }
      const unsigned long long wm = __ballot(pv == 0);
      __builtin_amdgcn_s_barrier();
      __builtin_amdgcn_sched_barrier(0);

      if (valid) {
        const int bufc = i & 1;
        if ((t != nT - 1) && wm == 0ull) step(ICb<false>{}, kb0, bufc, 0ull);
        else                             step(ICb<true >{}, kb0, bufc, wm);
      }
      __builtin_amdgcn_s_barrier();
    }

    // per-group l reduce (lane holds row q_'s partial over its key subset)
    float lt = lsum + __shfl_xor(lsum, 16);
    lt += __shfl_xor(lt, 32);

    // merge: group1 -> LDS (f32 numerators + l), group0 adds + normalizes
    if (grp == 1) {
#pragma unroll
      for (int r = 0; r < 4; ++r)
#pragma unroll
        for (int n = 0; n < 4; ++n)
          LOf[(wid4*16 + koff + r)*64 + n*16 + q_] = Oacc[n][r];
      if (hi4 == 0) Ll[wid4*16 + q_] = lt;
    }
    __syncthreads();
    if (grp == 0) {
#pragma unroll
      for (int r = 0; r < 4; ++r) {
        const int rloc = wid4*16 + koff + r;
        const float inv = 1.f / (__shfl(lt, koff + r) + Ll[rloc]);
        const int row = bi*SEQ + qbase + rloc;
#pragma unroll
        for (int n = 0; n < 4; ++n) {
          const float o = Oacc[n][r] + LOf[rloc*64 + n*16 + q_];
          ((__bf16*)outb)[(size_t)row*DMODEL + h*HDIM + n*16 + q_] = (__bf16)(o * inv);
        }
      }
    }
    __syncthreads();   // merge reads done -> next half may restage over Ks/Ps
  }
#undef STAGE
}

extern "C" void kernel_launch(void* const* d_in, const int* in_sizes, int n_in,
                              void* d_out, int out_size, void* d_ws, size_t ws_size,
                              hipStream_t stream)
{
  const float* x  = (const float*)d_in[0];
  const int*   ids= (const int*)d_in[1];
  const float* Wq = (const float*)d_in[2];
  const float* bq = (const float*)d_in[3];
  const float* Wk = (const float*)d_in[4];
  const float* bk = (const float*)d_in[5];
  const float* Wv = (const float*)d_in[6];
  const float* bv = (const float*)d_in[7];
  const float* Wo = (const float*)d_in[8];
  const float* bo = (const float*)d_in[9];
  float* out = (float*)d_out;

  char* ws = (char*)d_ws;
  unsigned short* xb   = (unsigned short*)(ws);
  unsigned short* wqb  = (unsigned short*)(ws + ( 8u<<20));
  unsigned short* wkb  = (unsigned short*)(ws + (10u<<20));
  unsigned short* wvb  = (unsigned short*)(ws + (12u<<20));
  unsigned short* wob  = (unsigned short*)(ws + (14u<<20));
  unsigned short* qbuf = (unsigned short*)(ws + (16u<<20));
  unsigned short* kbuf = (unsigned short*)(ws + (24u<<20));
  unsigned short* vbuf = (unsigned short*)(ws + (32u<<20));  // [b,h,d,s]
  unsigned short* abuf = (unsigned short*)(ws + (40u<<20));

  cast_all<<<8192, 256, 0, stream>>>(x, Wq, Wk, Wv, Wo,
                                     (__bf16*)xb, (__bf16*)wqb, (__bf16*)wkb,
                                     (__bf16*)wvb, (__bf16*)wob);

  gemm_nt<0><<<768, 256, 0, stream>>>(xb, wqb, wkb, wvb, bq, bk, bv,
                                      qbuf, kbuf, vbuf, nullptr);

  attn_fwd<<<dim3(32, 16), 512, 0, stream>>>(qbuf, kbuf, vbuf, ids, abuf);

  gemm_nt<1><<<256, 256, 0, stream>>>(abuf, wob, wob, wob, bo, bo, bo,
                                      nullptr, nullptr, nullptr, out);
}